// Round 1
// baseline (267.577 us; speedup 1.0000x reference)
//
#include <hip/hip_runtime.h>
#include <stdint.h>

#define NSEQ 256
#define NRES 256
#define CM   256
#define CZ   128
#define CH   32
#define NHEAD 8
#define EPSF 1e-5f

typedef __bf16 bf16x8 __attribute__((ext_vector_type(8)));
typedef float  f32x4  __attribute__((ext_vector_type(4)));

__device__ __forceinline__ ushort f2bf(float f) {
    union { float f; uint32_t u; } v; v.f = f;
    uint32_t r = (v.u + 0x7FFFu + ((v.u >> 16) & 1u)) >> 16;
    return (ushort)r;
}
__device__ __forceinline__ float bf2f(ushort h) {
    union { uint32_t u; float f; } v; v.u = ((uint32_t)h) << 16;
    return v.f;
}

// ---------------------------------------------------------------- prep weights
// Wt[n][k] = W*[k][n] (bf16), n in [0,1024): 0-255 Wq*1/sqrt(32), 256-511 Wk,
// 512-767 Wv, 768-1023 Wg.  WoT[n][k] = Wo[k][n] (bf16), n in [0,256).
__global__ void prep_weights_kernel(const float* __restrict__ Wq,
                                    const float* __restrict__ Wk,
                                    const float* __restrict__ Wv,
                                    const float* __restrict__ Wg,
                                    const float* __restrict__ Wo,
                                    ushort* __restrict__ Wt,
                                    ushort* __restrict__ WoT) {
    int n = blockIdx.x;
    int k = threadIdx.x;
    if (n < 1024) {
        int nn = n & 255;
        const float* src;
        float scale = 1.0f;
        if      (n < 256) { src = Wq; scale = 0.17677669529663687f; }
        else if (n < 512) { src = Wk; }
        else if (n < 768) { src = Wv; }
        else              { src = Wg; }
        Wt[n * 256 + k] = f2bf(src[k * 256 + nn] * scale);
    } else {
        int nn = n - 1024;
        WoT[nn * 256 + k] = f2bf(Wo[k * 256 + nn]);
    }
}

// ---------------------------------------------------------------- LayerNorm(m)
// one wave per row of 256; output bf16
__global__ __launch_bounds__(256) void ln_m_kernel(const float* __restrict__ m,
                                                   const float* __restrict__ w,
                                                   const float* __restrict__ b,
                                                   ushort* __restrict__ mn) {
    int gw   = (blockIdx.x * blockDim.x + threadIdx.x) >> 6;   // row id
    int lane = threadIdx.x & 63;
    const float* row = m + (size_t)gw * 256;
    float4 x = *(const float4*)(row + lane * 4);
    float s  = x.x + x.y + x.z + x.w;
    float sq = x.x * x.x + x.y * x.y + x.z * x.z + x.w * x.w;
#pragma unroll
    for (int off = 32; off; off >>= 1) {
        s  += __shfl_xor(s, off, 64);
        sq += __shfl_xor(sq, off, 64);
    }
    float mu  = s * (1.0f / 256.0f);
    float var = sq * (1.0f / 256.0f) - mu * mu;
    float rs  = rsqrtf(var + EPSF);
    float4 wv = *(const float4*)(w + lane * 4);
    float4 bv = *(const float4*)(b + lane * 4);
    ushort4 o;
    o.x = f2bf((x.x - mu) * rs * wv.x + bv.x);
    o.y = f2bf((x.y - mu) * rs * wv.y + bv.y);
    o.z = f2bf((x.z - mu) * rs * wv.z + bv.z);
    o.w = f2bf((x.w - mu) * rs * wv.w + bv.w);
    *(ushort4*)(mn + (size_t)gw * 256 + lane * 4) = o;
}

// ---------------------------------------------------------- LayerNorm(z) @ Wz
// one wave per (i,j) row of 128; writes bias[h][i][j] fp32
__global__ __launch_bounds__(256) void ln_z_bias_kernel(const float* __restrict__ z,
                                                        const float* __restrict__ w,
                                                        const float* __restrict__ b,
                                                        const float* __restrict__ Wz,
                                                        float* __restrict__ bias) {
    int gw   = (blockIdx.x * blockDim.x + threadIdx.x) >> 6;   // wave 0..8191
    int lane = threadIdx.x & 63;
    float wz0[8], wz1[8];
#pragma unroll
    for (int h = 0; h < 8; ++h) {
        wz0[h] = Wz[(2 * lane) * 8 + h];
        wz1[h] = Wz[(2 * lane + 1) * 8 + h];
    }
    float w0 = w[2 * lane], w1 = w[2 * lane + 1];
    float b0 = b[2 * lane], b1 = b[2 * lane + 1];
    for (int row = gw; row < 65536; row += 8192) {
        float2 x = *(const float2*)(z + (size_t)row * 128 + 2 * lane);
        float s = x.x + x.y, sq = x.x * x.x + x.y * x.y;
#pragma unroll
        for (int off = 32; off; off >>= 1) {
            s  += __shfl_xor(s, off, 64);
            sq += __shfl_xor(sq, off, 64);
        }
        float mu = s * (1.0f / 128.0f);
        float rs = rsqrtf(sq * (1.0f / 128.0f) - mu * mu + EPSF);
        float z0 = (x.x - mu) * rs * w0 + b0;
        float z1 = (x.y - mu) * rs * w1 + b1;
        float acc[8];
#pragma unroll
        for (int h = 0; h < 8; ++h) acc[h] = z0 * wz0[h] + z1 * wz1[h];
#pragma unroll
        for (int h = 0; h < 8; ++h)
#pragma unroll
            for (int off = 32; off; off >>= 1) acc[h] += __shfl_xor(acc[h], off, 64);
        if (lane < 8) bias[lane * 65536 + row] = acc[lane];
    }
}

// ------------------------------------------------------------ projection GEMM
// mn (65536x256) @ Wt^T (256x1024) -> Q,K (S,H,R,C) ; Vt (S,H,C,R) ; G sigmoid
#define LPAD 72
__global__ __launch_bounds__(256) void proj_gemm_kernel(const ushort* __restrict__ mn,
                                                        const ushort* __restrict__ Wt,
                                                        const float* __restrict__ bg,
                                                        ushort* __restrict__ Q,
                                                        ushort* __restrict__ K,
                                                        ushort* __restrict__ Vt,
                                                        ushort* __restrict__ G) {
    __shared__ ushort Ash[64][LPAD];
    __shared__ ushort Bsh[64][LPAD];
    int bm = blockIdx.y, bn = blockIdx.x;
    int t = threadIdx.x, w = t >> 6, lane = t & 63;
    int l15 = lane & 15, l4 = lane >> 4;
    int m0 = bm * 64, n0 = bn * 64;
    int srow = t >> 3, sseg = t & 7;
    f32x4 acc[4] = {};

    for (int kt = 0; kt < 4; ++kt) {
        int k0 = kt * 64;
        __syncthreads();
        *(uint4*)&Ash[srow][sseg * 8]      = *(const uint4*)&mn[(size_t)(m0 + srow) * 256 + k0 + sseg * 8];
        *(uint4*)&Ash[srow + 32][sseg * 8] = *(const uint4*)&mn[(size_t)(m0 + srow + 32) * 256 + k0 + sseg * 8];
        *(uint4*)&Bsh[srow][sseg * 8]      = *(const uint4*)&Wt[(size_t)(n0 + srow) * 256 + k0 + sseg * 8];
        *(uint4*)&Bsh[srow + 32][sseg * 8] = *(const uint4*)&Wt[(size_t)(n0 + srow + 32) * 256 + k0 + sseg * 8];
        __syncthreads();
#pragma unroll
        for (int ks = 0; ks < 2; ++ks) {
            bf16x8 a = *(const bf16x8*)&Ash[w * 16 + l15][ks * 32 + l4 * 8];
#pragma unroll
            for (int nt = 0; nt < 4; ++nt) {
                bf16x8 bb = *(const bf16x8*)&Bsh[nt * 16 + l15][ks * 32 + l4 * 8];
                acc[nt] = __builtin_amdgcn_mfma_f32_16x16x32_bf16(a, bb, acc[nt], 0, 0, 0);
            }
        }
    }

    int mrow = m0 + w * 16 + l4 * 4;        // + reg
    int ss = mrow >> 8;                      // seq index (constant over 4 regs)
    int region = bn >> 2;                    // 0=Q 1=K 2=V 3=G (block-uniform)
#pragma unroll
    for (int nt = 0; nt < 4; ++nt) {
        int n = n0 + nt * 16 + l15;
        if (region == 0) {
            int h = n >> 5, c = n & 31;
#pragma unroll
            for (int r = 0; r < 4; ++r) {
                int rr = (mrow + r) & 255;
                Q[((size_t)(ss * 8 + h) * 256 + rr) * 32 + c] = f2bf(acc[nt][r]);
            }
        } else if (region == 1) {
            int nn = n - 256, h = nn >> 5, c = nn & 31;
#pragma unroll
            for (int r = 0; r < 4; ++r) {
                int rr = (mrow + r) & 255;
                K[((size_t)(ss * 8 + h) * 256 + rr) * 32 + c] = f2bf(acc[nt][r]);
            }
        } else if (region == 2) {
            int nn = n - 512, h = nn >> 5, c = nn & 31;
            ushort4 pv;
            pv.x = f2bf(acc[nt][0]); pv.y = f2bf(acc[nt][1]);
            pv.z = f2bf(acc[nt][2]); pv.w = f2bf(acc[nt][3]);
            int rr0 = mrow & 255;
            *(ushort4*)&Vt[((size_t)(ss * 8 + h) * 32 + c) * 256 + rr0] = pv;
        } else {
            int nn = n - 768;
            float bgv = bg[nn];
#pragma unroll
            for (int r = 0; r < 4; ++r) {
                int rr = (mrow + r) & 255;
                float x = acc[nt][r] + bgv;
                float g = 1.0f / (1.0f + __expf(-x));
                G[((size_t)(ss * 256 + rr)) * 256 + nn] = f2bf(g);
            }
        }
    }
}

// ----------------------------------------------------------------- attention
// block = (rowblock, h, s); 4 waves x 16 query rows; full 256-key softmax
__global__ __launch_bounds__(256) void attn_kernel(const ushort* __restrict__ Q,
                                                   const ushort* __restrict__ K,
                                                   const ushort* __restrict__ Vt,
                                                   const ushort* __restrict__ G,
                                                   const float* __restrict__ bias,
                                                   ushort* __restrict__ GO) {
    __shared__ __align__(16) char smem[50688];
    ushort (*Ksh)[40]  = (ushort(*)[40])smem;            // 256x40  = 20480 B
    ushort (*Psh)[264] = (ushort(*)[264])smem;           // 64x264  = 33792 B (aliases Ksh)
    ushort (*Vsh)[264] = (ushort(*)[264])(smem + 33792); // 32x264  = 16896 B

    int rb = blockIdx.x, h = blockIdx.y, s = blockIdx.z;
    int t = threadIdx.x, w = t >> 6, lane = t & 63;
    int l15 = lane & 15, l4 = lane >> 4;

    const ushort* Kb = K  + (size_t)(s * 8 + h) * 8192;
    const ushort* Vb = Vt + (size_t)(s * 8 + h) * 8192;
#pragma unroll
    for (int it = 0; it < 4; ++it) {
        int row = it * 64 + (t >> 2), seg = t & 3;
        *(uint4*)&Ksh[row][seg * 8] = *(const uint4*)&Kb[row * 32 + seg * 8];
    }
#pragma unroll
    for (int it = 0; it < 4; ++it) {
        int row = it * 8 + (t >> 5), seg = t & 31;
        *(uint4*)&Vsh[row][seg * 8] = *(const uint4*)&Vb[row * 256 + seg * 8];
    }
    __syncthreads();

    int qr0 = rb * 64 + w * 16;
    const ushort* Qb = Q + (size_t)(s * 8 + h) * 8192;
    bf16x8 qf = *(const bf16x8*)&Qb[(qr0 + l15) * 32 + l4 * 8];

    const f32x4 zf = {0.f, 0.f, 0.f, 0.f};
    f32x4 sc[16];
#pragma unroll
    for (int nt = 0; nt < 16; ++nt) {
        bf16x8 kf = *(const bf16x8*)&Ksh[nt * 16 + l15][l4 * 8];
        sc[nt] = __builtin_amdgcn_mfma_f32_16x16x32_bf16(qf, kf, zf, 0, 0, 0);
    }

    // bias add (fp32), then row softmax (rows = l4*4 + r, 16 lanes per row)
    const float* bb = bias + (size_t)h * 65536 + (size_t)(qr0 + l4 * 4) * 256 + l15;
    float rinv[4];
#pragma unroll
    for (int r = 0; r < 4; ++r) {
#pragma unroll
        for (int nt = 0; nt < 16; ++nt) sc[nt][r] += bb[r * 256 + nt * 16];
    }
#pragma unroll
    for (int r = 0; r < 4; ++r) {
        float mx = -1e30f;
#pragma unroll
        for (int nt = 0; nt < 16; ++nt) mx = fmaxf(mx, sc[nt][r]);
#pragma unroll
        for (int off = 1; off < 16; off <<= 1) mx = fmaxf(mx, __shfl_xor(mx, off, 64));
        float sm = 0.f;
#pragma unroll
        for (int nt = 0; nt < 16; ++nt) {
            float p = __expf(sc[nt][r] - mx);
            sc[nt][r] = p;
            sm += p;
        }
#pragma unroll
        for (int off = 1; off < 16; off <<= 1) sm += __shfl_xor(sm, off, 64);
        rinv[r] = 1.0f / sm;
    }

    __syncthreads();   // everyone done reading Ksh before P overwrites it
#pragma unroll
    for (int r = 0; r < 4; ++r)
#pragma unroll
        for (int nt = 0; nt < 16; ++nt)
            Psh[w * 16 + l4 * 4 + r][nt * 16 + l15] = f2bf(sc[nt][r]);
    __syncthreads();

    f32x4 oacc[2] = {};
#pragma unroll
    for (int ks = 0; ks < 8; ++ks) {
        bf16x8 pf = *(const bf16x8*)&Psh[w * 16 + l15][ks * 32 + l4 * 8];
#pragma unroll
        for (int nt = 0; nt < 2; ++nt) {
            bf16x8 vf = *(const bf16x8*)&Vsh[nt * 16 + l15][ks * 32 + l4 * 8];
            oacc[nt] = __builtin_amdgcn_mfma_f32_16x16x32_bf16(pf, vf, oacc[nt], 0, 0, 0);
        }
    }

    const ushort* Gb = G + (size_t)s * 65536;
#pragma unroll
    for (int nt = 0; nt < 2; ++nt) {
        int c = nt * 16 + l15;
#pragma unroll
        for (int r = 0; r < 4; ++r) {
            int qr = qr0 + l4 * 4 + r;
            float gv = bf2f(Gb[qr * 256 + h * 32 + c]);
            float ov = oacc[nt][r] * rinv[r] * gv;
            GO[((size_t)s * 256 + qr) * 256 + h * 32 + c] = f2bf(ov);
        }
    }
}

// -------------------------------------------------------------- output GEMM
// GO (65536x256) @ WoT^T (256x256) + bo -> out fp32
__global__ __launch_bounds__(256) void out_gemm_kernel(const ushort* __restrict__ GO,
                                                       const ushort* __restrict__ WoT,
                                                       const float* __restrict__ bo,
                                                       float* __restrict__ out) {
    __shared__ ushort Ash[64][LPAD];
    __shared__ ushort Bsh[64][LPAD];
    int bm = blockIdx.y, bn = blockIdx.x;
    int t = threadIdx.x, w = t >> 6, lane = t & 63;
    int l15 = lane & 15, l4 = lane >> 4;
    int m0 = bm * 64, n0 = bn * 64;
    int srow = t >> 3, sseg = t & 7;
    f32x4 acc[4] = {};

    for (int kt = 0; kt < 4; ++kt) {
        int k0 = kt * 64;
        __syncthreads();
        *(uint4*)&Ash[srow][sseg * 8]      = *(const uint4*)&GO[(size_t)(m0 + srow) * 256 + k0 + sseg * 8];
        *(uint4*)&Ash[srow + 32][sseg * 8] = *(const uint4*)&GO[(size_t)(m0 + srow + 32) * 256 + k0 + sseg * 8];
        *(uint4*)&Bsh[srow][sseg * 8]      = *(const uint4*)&WoT[(size_t)(n0 + srow) * 256 + k0 + sseg * 8];
        *(uint4*)&Bsh[srow + 32][sseg * 8] = *(const uint4*)&WoT[(size_t)(n0 + srow + 32) * 256 + k0 + sseg * 8];
        __syncthreads();
#pragma unroll
        for (int ks = 0; ks < 2; ++ks) {
            bf16x8 a = *(const bf16x8*)&Ash[w * 16 + l15][ks * 32 + l4 * 8];
#pragma unroll
            for (int nt = 0; nt < 4; ++nt) {
                bf16x8 bb = *(const bf16x8*)&Bsh[nt * 16 + l15][ks * 32 + l4 * 8];
                acc[nt] = __builtin_amdgcn_mfma_f32_16x16x32_bf16(a, bb, acc[nt], 0, 0, 0);
            }
        }
    }

    int mrow = m0 + w * 16 + l4 * 4;
#pragma unroll
    for (int nt = 0; nt < 4; ++nt) {
        int n = n0 + nt * 16 + l15;
        float bov = bo[n];
#pragma unroll
        for (int r = 0; r < 4; ++r) {
            out[(size_t)(mrow + r) * 256 + n] = acc[nt][r] + bov;
        }
    }
}

// ------------------------------------------------------------------- launch
extern "C" void kernel_launch(void* const* d_in, const int* in_sizes, int n_in,
                              void* d_out, int out_size, void* d_ws, size_t ws_size,
                              hipStream_t stream) {
    const float* m      = (const float*)d_in[0];
    const float* z      = (const float*)d_in[1];
    const float* ln_m_w = (const float*)d_in[2];
    const float* ln_m_b = (const float*)d_in[3];
    const float* ln_z_w = (const float*)d_in[4];
    const float* ln_z_b = (const float*)d_in[5];
    const float* Wz     = (const float*)d_in[6];
    const float* Wq     = (const float*)d_in[7];
    const float* Wk     = (const float*)d_in[8];
    const float* Wv     = (const float*)d_in[9];
    const float* Wg     = (const float*)d_in[10];
    const float* bg     = (const float*)d_in[11];
    const float* Wo     = (const float*)d_in[12];
    const float* bo     = (const float*)d_in[13];
    float* out = (float*)d_out;

    char* ws = (char*)d_ws;
    ushort* Wt   = (ushort*)(ws + 0);            //  524288 B
    ushort* WoT  = (ushort*)(ws + 524288);       //  131072 B
    float*  bias = (float*) (ws + 655360);       // 2097152 B
    ushort* mn   = (ushort*)(ws + 2752512);      // 33554432 B (aliased with GO)
    ushort* GO   = mn;
    ushort* Q    = (ushort*)(ws + 36306944);     // 33554432 B
    ushort* K    = (ushort*)(ws + 69861376);     // 33554432 B
    ushort* Vt   = (ushort*)(ws + 103415808);    // 33554432 B
    ushort* G    = (ushort*)(ws + 136970240);    // 33554432 B

    prep_weights_kernel<<<1280, 256, 0, stream>>>(Wq, Wk, Wv, Wg, Wo, Wt, WoT);
    ln_m_kernel<<<16384, 256, 0, stream>>>(m, ln_m_w, ln_m_b, mn);
    ln_z_bias_kernel<<<2048, 256, 0, stream>>>(z, ln_z_w, ln_z_b, Wz, bias);
    proj_gemm_kernel<<<dim3(16, 1024), 256, 0, stream>>>(mn, Wt, bg, Q, K, Vt, G);
    attn_kernel<<<dim3(4, 8, 256), 256, 0, stream>>>(Q, K, Vt, G, bias, GO);
    out_gemm_kernel<<<dim3(4, 1024), 256, 0, stream>>>(GO, WoT, bo, out);
}

// Round 2
// 253.518 us; speedup vs baseline: 1.0555x; 1.0555x over previous
//
#include <hip/hip_runtime.h>
#include <stdint.h>

#define NSEQ 256
#define NRES 256
#define CM   256
#define CZ   128
#define CH   32
#define NHEAD 8
#define EPSF 1e-5f

typedef __bf16 bf16x8 __attribute__((ext_vector_type(8)));
typedef float  f32x4  __attribute__((ext_vector_type(4)));

__device__ __forceinline__ ushort f2bf(float f) {
    union { float f; uint32_t u; } v; v.f = f;
    uint32_t r = (v.u + 0x7FFFu + ((v.u >> 16) & 1u)) >> 16;
    return (ushort)r;
}
__device__ __forceinline__ float bf2f(ushort h) {
    union { uint32_t u; float f; } v; v.u = ((uint32_t)h) << 16;
    return v.f;
}

__device__ __forceinline__ void gload16(const void* g, void* l) {
    __builtin_amdgcn_global_load_lds(
        (const __attribute__((address_space(1))) void*)g,
        (__attribute__((address_space(3))) void*)l,
        16, 0, 0);
}

// ---------------------------------------------------------------- prep weights
__global__ void prep_weights_kernel(const float* __restrict__ Wq,
                                    const float* __restrict__ Wk,
                                    const float* __restrict__ Wv,
                                    const float* __restrict__ Wg,
                                    const float* __restrict__ Wo,
                                    ushort* __restrict__ Wt,
                                    ushort* __restrict__ WoT) {
    int n = blockIdx.x;
    int k = threadIdx.x;
    if (n < 1024) {
        int nn = n & 255;
        const float* src;
        float scale = 1.0f;
        if      (n < 256) { src = Wq; scale = 0.17677669529663687f; }
        else if (n < 512) { src = Wk; }
        else if (n < 768) { src = Wv; }
        else              { src = Wg; }
        Wt[n * 256 + k] = f2bf(src[k * 256 + nn] * scale);
    } else {
        int nn = n - 1024;
        WoT[nn * 256 + k] = f2bf(Wo[k * 256 + nn]);
    }
}

// ---------------------------------------------------------------- LayerNorm(m)
__global__ __launch_bounds__(256) void ln_m_kernel(const float* __restrict__ m,
                                                   const float* __restrict__ w,
                                                   const float* __restrict__ b,
                                                   ushort* __restrict__ mn) {
    int gw   = (blockIdx.x * blockDim.x + threadIdx.x) >> 6;
    int lane = threadIdx.x & 63;
    const float* row = m + (size_t)gw * 256;
    float4 x = *(const float4*)(row + lane * 4);
    float s  = x.x + x.y + x.z + x.w;
    float sq = x.x * x.x + x.y * x.y + x.z * x.z + x.w * x.w;
#pragma unroll
    for (int off = 32; off; off >>= 1) {
        s  += __shfl_xor(s, off, 64);
        sq += __shfl_xor(sq, off, 64);
    }
    float mu  = s * (1.0f / 256.0f);
    float var = sq * (1.0f / 256.0f) - mu * mu;
    float rs  = rsqrtf(var + EPSF);
    float4 wv = *(const float4*)(w + lane * 4);
    float4 bv = *(const float4*)(b + lane * 4);
    ushort4 o;
    o.x = f2bf((x.x - mu) * rs * wv.x + bv.x);
    o.y = f2bf((x.y - mu) * rs * wv.y + bv.y);
    o.z = f2bf((x.z - mu) * rs * wv.z + bv.z);
    o.w = f2bf((x.w - mu) * rs * wv.w + bv.w);
    *(ushort4*)(mn + (size_t)gw * 256 + lane * 4) = o;
}

// ---------------------------------------------------------- LayerNorm(z) @ Wz
__global__ __launch_bounds__(256) void ln_z_bias_kernel(const float* __restrict__ z,
                                                        const float* __restrict__ w,
                                                        const float* __restrict__ b,
                                                        const float* __restrict__ Wz,
                                                        float* __restrict__ bias) {
    int gw   = (blockIdx.x * blockDim.x + threadIdx.x) >> 6;
    int lane = threadIdx.x & 63;
    float wz0[8], wz1[8];
#pragma unroll
    for (int h = 0; h < 8; ++h) {
        wz0[h] = Wz[(2 * lane) * 8 + h];
        wz1[h] = Wz[(2 * lane + 1) * 8 + h];
    }
    float w0 = w[2 * lane], w1 = w[2 * lane + 1];
    float b0 = b[2 * lane], b1 = b[2 * lane + 1];
    for (int row = gw; row < 65536; row += 8192) {
        float2 x = *(const float2*)(z + (size_t)row * 128 + 2 * lane);
        float s = x.x + x.y, sq = x.x * x.x + x.y * x.y;
#pragma unroll
        for (int off = 32; off; off >>= 1) {
            s  += __shfl_xor(s, off, 64);
            sq += __shfl_xor(sq, off, 64);
        }
        float mu = s * (1.0f / 128.0f);
        float rs = rsqrtf(sq * (1.0f / 128.0f) - mu * mu + EPSF);
        float z0 = (x.x - mu) * rs * w0 + b0;
        float z1 = (x.y - mu) * rs * w1 + b1;
        float acc[8];
#pragma unroll
        for (int h = 0; h < 8; ++h) acc[h] = z0 * wz0[h] + z1 * wz1[h];
#pragma unroll
        for (int h = 0; h < 8; ++h)
#pragma unroll
            for (int off = 32; off; off >>= 1) acc[h] += __shfl_xor(acc[h], off, 64);
        if (lane < 8) bias[lane * 65536 + row] = acc[lane];
    }
}

// ------------------------------------------------------------ projection GEMM
// 128x128 tile, BK=64, global_load_lds + XOR-swizzle, XCD-chunked swizzle.
// mn (65536x256) @ Wt^T -> Q,K (S,H,R,C); Vt (S,H,C,R); G sigmoid (S*R, 256)
__global__ __launch_bounds__(256) void proj_gemm_kernel(const ushort* __restrict__ mn,
                                                        const ushort* __restrict__ Wt,
                                                        const float* __restrict__ bg,
                                                        ushort* __restrict__ Q,
                                                        ushort* __restrict__ K,
                                                        ushort* __restrict__ Vt,
                                                        ushort* __restrict__ G) {
    __shared__ ushort Ash[8192];   // [128][64] linear, XOR-swizzled granules
    __shared__ ushort Bsh[8192];
    int bid = blockIdx.x;                          // 4096 blocks
    int wid = ((bid & 7) << 9) | (bid >> 3);       // XCD chunk of 512
    int by = wid >> 3, bx = wid & 7;
    int m0 = by << 7, n0 = bx << 7;
    int t = threadIdx.x, lane = t & 63, w = t >> 6;
    int l15 = lane & 15, l4 = lane >> 4;
    int wr = w >> 1, wc = w & 1;

    int srow  = t >> 3;                                       // 0..31 (+32/issue)
    int scolh = (((lane & 7) ^ ((lane >> 3) & 7)) << 3);      // pre-swizzled src col (halves)
    const ushort* Ag = mn + (size_t)(m0 + srow) * 256 + scolh;
    const ushort* Bg = Wt + (size_t)(n0 + srow) * 256 + scolh;
    ushort* Al = Ash + t * 8;
    ushort* Bl = Bsh + t * 8;

    f32x4 acc[4][4] = {};

    for (int kt = 0; kt < 4; ++kt) {
        int k0 = kt << 6;
        __syncthreads();
#pragma unroll
        for (int i = 0; i < 4; ++i) {
            gload16(Ag + (size_t)(i * 32) * 256 + k0, Al + i * 2048);
            gload16(Bg + (size_t)(i * 32) * 256 + k0, Bl + i * 2048);
        }
        __syncthreads();
#pragma unroll
        for (int ks = 0; ks < 2; ++ks) {
            int xr = ks * 4 + l4;
            bf16x8 af[4], bfr[4];
#pragma unroll
            for (int mi = 0; mi < 4; ++mi) {
                int row = wr * 64 + mi * 16 + l15;
                af[mi] = *(const bf16x8*)&Ash[row * 64 + ((xr ^ (l15 & 7)) << 3)];
            }
#pragma unroll
            for (int ni = 0; ni < 4; ++ni) {
                int row = wc * 64 + ni * 16 + l15;
                bfr[ni] = *(const bf16x8*)&Bsh[row * 64 + ((xr ^ (l15 & 7)) << 3)];
            }
#pragma unroll
            for (int mi = 0; mi < 4; ++mi)
#pragma unroll
                for (int ni = 0; ni < 4; ++ni)
                    acc[mi][ni] = __builtin_amdgcn_mfma_f32_16x16x32_bf16(af[mi], bfr[ni], acc[mi][ni], 0, 0, 0);
        }
    }

    int region = bx >> 1;                 // 0=Q 1=K 2=V 3=G
    int ss = m0 >> 8;                     // block-uniform sequence index
    int rbase = (m0 & 255) + wr * 64 + l4 * 4;

    if (region <= 1) {
        ushort* dst = (region == 0) ? Q : K;
#pragma unroll
        for (int ni = 0; ni < 4; ++ni) {
            int nn = (n0 & 255) + wc * 64 + ni * 16 + l15;
            int h = nn >> 5, c = nn & 31;
            size_t base = (size_t)(ss * 8 + h) * 8192 + c;
#pragma unroll
            for (int mi = 0; mi < 4; ++mi) {
                int rr = rbase + mi * 16;
#pragma unroll
                for (int r = 0; r < 4; ++r)
                    dst[base + (size_t)(rr + r) * 32] = f2bf(acc[mi][ni][r]);
            }
        }
    } else if (region == 2) {
#pragma unroll
        for (int ni = 0; ni < 4; ++ni) {
            int nn = (n0 & 255) + wc * 64 + ni * 16 + l15;
            int h = nn >> 5, c = nn & 31;
#pragma unroll
            for (int mi = 0; mi < 4; ++mi) {
                int rr = rbase + mi * 16;
                ushort4 pv;
                pv.x = f2bf(acc[mi][ni][0]); pv.y = f2bf(acc[mi][ni][1]);
                pv.z = f2bf(acc[mi][ni][2]); pv.w = f2bf(acc[mi][ni][3]);
                *(ushort4*)&Vt[((size_t)(ss * 8 + h) * 32 + c) * 256 + rr] = pv;
            }
        }
    } else {
#pragma unroll
        for (int ni = 0; ni < 4; ++ni) {
            int nn = (n0 & 255) + wc * 64 + ni * 16 + l15;
            float bgv = bg[nn];
#pragma unroll
            for (int mi = 0; mi < 4; ++mi) {
                int rr = rbase + mi * 16;
#pragma unroll
                for (int r = 0; r < 4; ++r) {
                    float x = acc[mi][ni][r] + bgv;
                    G[(size_t)(ss * 256 + rr + r) * 256 + nn] = f2bf(1.0f / (1.0f + __expf(-x)));
                }
            }
        }
    }
}

// ----------------------------------------------------------------- attention
__global__ __launch_bounds__(256) void attn_kernel(const ushort* __restrict__ Q,
                                                   const ushort* __restrict__ K,
                                                   const ushort* __restrict__ Vt,
                                                   const ushort* __restrict__ G,
                                                   const float* __restrict__ bias,
                                                   ushort* __restrict__ GO) {
    __shared__ __align__(16) char smem[50688];
    ushort (*Ksh)[40]  = (ushort(*)[40])smem;            // 256x40  = 20480 B
    ushort (*Psh)[264] = (ushort(*)[264])smem;           // 64x264  = 33792 B (aliases Ksh)
    ushort (*Vsh)[264] = (ushort(*)[264])(smem + 33792); // 32x264  = 16896 B

    int rb = blockIdx.x, h = blockIdx.y, s = blockIdx.z;
    int t = threadIdx.x, w = t >> 6, lane = t & 63;
    int l15 = lane & 15, l4 = lane >> 4;

    const ushort* Kb = K  + (size_t)(s * 8 + h) * 8192;
    const ushort* Vb = Vt + (size_t)(s * 8 + h) * 8192;
#pragma unroll
    for (int it = 0; it < 4; ++it) {
        int row = it * 64 + (t >> 2), seg = t & 3;
        *(uint4*)&Ksh[row][seg * 8] = *(const uint4*)&Kb[row * 32 + seg * 8];
    }
#pragma unroll
    for (int it = 0; it < 4; ++it) {
        int row = it * 8 + (t >> 5), seg = t & 31;
        *(uint4*)&Vsh[row][seg * 8] = *(const uint4*)&Vb[row * 256 + seg * 8];
    }
    __syncthreads();

    int qr0 = rb * 64 + w * 16;
    const ushort* Qb = Q + (size_t)(s * 8 + h) * 8192;
    bf16x8 qf = *(const bf16x8*)&Qb[(qr0 + l15) * 32 + l4 * 8];

    const f32x4 zf = {0.f, 0.f, 0.f, 0.f};
    f32x4 sc[16];
#pragma unroll
    for (int nt = 0; nt < 16; ++nt) {
        bf16x8 kf = *(const bf16x8*)&Ksh[nt * 16 + l15][l4 * 8];
        sc[nt] = __builtin_amdgcn_mfma_f32_16x16x32_bf16(qf, kf, zf, 0, 0, 0);
    }

    const float* bb = bias + (size_t)h * 65536 + (size_t)(qr0 + l4 * 4) * 256 + l15;
    float rinv[4];
#pragma unroll
    for (int r = 0; r < 4; ++r) {
#pragma unroll
        for (int nt = 0; nt < 16; ++nt) sc[nt][r] += bb[r * 256 + nt * 16];
    }
#pragma unroll
    for (int r = 0; r < 4; ++r) {
        float mx = -1e30f;
#pragma unroll
        for (int nt = 0; nt < 16; ++nt) mx = fmaxf(mx, sc[nt][r]);
#pragma unroll
        for (int off = 1; off < 16; off <<= 1) mx = fmaxf(mx, __shfl_xor(mx, off, 64));
        float sm = 0.f;
#pragma unroll
        for (int nt = 0; nt < 16; ++nt) {
            float p = __expf(sc[nt][r] - mx);
            sc[nt][r] = p;
            sm += p;
        }
#pragma unroll
        for (int off = 1; off < 16; off <<= 1) sm += __shfl_xor(sm, off, 64);
        rinv[r] = 1.0f / sm;
    }

    __syncthreads();
#pragma unroll
    for (int r = 0; r < 4; ++r)
#pragma unroll
        for (int nt = 0; nt < 16; ++nt)
            Psh[w * 16 + l4 * 4 + r][nt * 16 + l15] = f2bf(sc[nt][r]);
    __syncthreads();

    f32x4 oacc[2] = {};
#pragma unroll
    for (int ks = 0; ks < 8; ++ks) {
        bf16x8 pf = *(const bf16x8*)&Psh[w * 16 + l15][ks * 32 + l4 * 8];
#pragma unroll
        for (int nt = 0; nt < 2; ++nt) {
            bf16x8 vf = *(const bf16x8*)&Vsh[nt * 16 + l15][ks * 32 + l4 * 8];
            oacc[nt] = __builtin_amdgcn_mfma_f32_16x16x32_bf16(pf, vf, oacc[nt], 0, 0, 0);
        }
    }

    const ushort* Gb = G + (size_t)s * 65536;
#pragma unroll
    for (int nt = 0; nt < 2; ++nt) {
        int c = nt * 16 + l15;
#pragma unroll
        for (int r = 0; r < 4; ++r) {
            int qr = qr0 + l4 * 4 + r;
            float gv = bf2f(Gb[qr * 256 + h * 32 + c]);
            float ov = oacc[nt][r] * rinv[r] * gv;
            GO[((size_t)s * 256 + qr) * 256 + h * 32 + c] = f2bf(ov);
        }
    }
}

// -------------------------------------------------------------- output GEMM
// GO (65536x256) @ WoT^T (256x256) + bo -> out fp32; 128x128 tile
__global__ __launch_bounds__(256) void out_gemm_kernel(const ushort* __restrict__ GO,
                                                       const ushort* __restrict__ WoT,
                                                       const float* __restrict__ bo,
                                                       float* __restrict__ out) {
    __shared__ ushort Ash[8192];
    __shared__ ushort Bsh[8192];
    int bid = blockIdx.x;                          // 1024 blocks
    int wid = ((bid & 7) << 7) | (bid >> 3);       // XCD chunk of 128
    int by = wid >> 1, bx = wid & 1;
    int m0 = by << 7, n0 = bx << 7;
    int t = threadIdx.x, lane = t & 63, w = t >> 6;
    int l15 = lane & 15, l4 = lane >> 4;
    int wr = w >> 1, wc = w & 1;

    int srow  = t >> 3;
    int scolh = (((lane & 7) ^ ((lane >> 3) & 7)) << 3);
    const ushort* Ag = GO  + (size_t)(m0 + srow) * 256 + scolh;
    const ushort* Bg = WoT + (size_t)(n0 + srow) * 256 + scolh;
    ushort* Al = Ash + t * 8;
    ushort* Bl = Bsh + t * 8;

    f32x4 acc[4][4] = {};

    for (int kt = 0; kt < 4; ++kt) {
        int k0 = kt << 6;
        __syncthreads();
#pragma unroll
        for (int i = 0; i < 4; ++i) {
            gload16(Ag + (size_t)(i * 32) * 256 + k0, Al + i * 2048);
            gload16(Bg + (size_t)(i * 32) * 256 + k0, Bl + i * 2048);
        }
        __syncthreads();
#pragma unroll
        for (int ks = 0; ks < 2; ++ks) {
            int xr = ks * 4 + l4;
            bf16x8 af[4], bfr[4];
#pragma unroll
            for (int mi = 0; mi < 4; ++mi) {
                int row = wr * 64 + mi * 16 + l15;
                af[mi] = *(const bf16x8*)&Ash[row * 64 + ((xr ^ (l15 & 7)) << 3)];
            }
#pragma unroll
            for (int ni = 0; ni < 4; ++ni) {
                int row = wc * 64 + ni * 16 + l15;
                bfr[ni] = *(const bf16x8*)&Bsh[row * 64 + ((xr ^ (l15 & 7)) << 3)];
            }
#pragma unroll
            for (int mi = 0; mi < 4; ++mi)
#pragma unroll
                for (int ni = 0; ni < 4; ++ni)
                    acc[mi][ni] = __builtin_amdgcn_mfma_f32_16x16x32_bf16(af[mi], bfr[ni], acc[mi][ni], 0, 0, 0);
        }
    }

    int crow0 = m0 + wr * 64 + l4 * 4;
#pragma unroll
    for (int ni = 0; ni < 4; ++ni) {
        int col = n0 + wc * 64 + ni * 16 + l15;
        float bov = bo[col];
#pragma unroll
        for (int mi = 0; mi < 4; ++mi)
#pragma unroll
            for (int r = 0; r < 4; ++r)
                out[(size_t)(crow0 + mi * 16 + r) * 256 + col] = acc[mi][ni][r] + bov;
    }
}

// ------------------------------------------------------------------- launch
extern "C" void kernel_launch(void* const* d_in, const int* in_sizes, int n_in,
                              void* d_out, int out_size, void* d_ws, size_t ws_size,
                              hipStream_t stream) {
    const float* m      = (const float*)d_in[0];
    const float* z      = (const float*)d_in[1];
    const float* ln_m_w = (const float*)d_in[2];
    const float* ln_m_b = (const float*)d_in[3];
    const float* ln_z_w = (const float*)d_in[4];
    const float* ln_z_b = (const float*)d_in[5];
    const float* Wz     = (const float*)d_in[6];
    const float* Wq     = (const float*)d_in[7];
    const float* Wk     = (const float*)d_in[8];
    const float* Wv     = (const float*)d_in[9];
    const float* Wg     = (const float*)d_in[10];
    const float* bg     = (const float*)d_in[11];
    const float* Wo     = (const float*)d_in[12];
    const float* bo     = (const float*)d_in[13];
    float* out = (float*)d_out;

    char* ws = (char*)d_ws;
    ushort* Wt   = (ushort*)(ws + 0);            //  524288 B
    ushort* WoT  = (ushort*)(ws + 524288);       //  131072 B
    float*  bias = (float*) (ws + 655360);       // 2097152 B
    ushort* mn   = (ushort*)(ws + 2752512);      // 33554432 B (aliased with GO)
    ushort* GO   = mn;
    ushort* Q    = (ushort*)(ws + 36306944);     // 33554432 B
    ushort* K    = (ushort*)(ws + 69861376);     // 33554432 B
    ushort* Vt   = (ushort*)(ws + 103415808);    // 33554432 B
    ushort* G    = (ushort*)(ws + 136970240);    // 33554432 B

    prep_weights_kernel<<<1280, 256, 0, stream>>>(Wq, Wk, Wv, Wg, Wo, Wt, WoT);
    ln_m_kernel<<<16384, 256, 0, stream>>>(m, ln_m_w, ln_m_b, mn);
    ln_z_bias_kernel<<<2048, 256, 0, stream>>>(z, ln_z_w, ln_z_b, Wz, bias);
    proj_gemm_kernel<<<4096, 256, 0, stream>>>(mn, Wt, bg, Q, K, Vt, G);
    attn_kernel<<<dim3(4, 8, 256), 256, 0, stream>>>(Q, K, Vt, G, bias, GO);
    out_gemm_kernel<<<1024, 256, 0, stream>>>(GO, WoT, bo, out);
}